// Round 9
// baseline (446.817 us; speedup 1.0000x reference)
//
#include <hip/hip_runtime.h>
#include <math.h>

// MADE autoregressive sampler, v19: wave-internal pipelines.
// B=8192, D=64, CTX=256, H=512. Units sorted by degree (mh = h%63+1).
// Evidence v14-v18: every structure keeping block-wide barriers on the
// z->h1->h2->z chain lands >=180us (185/310/180/250/208); the chain's pure
// work is ~4x cheaper. Fix: each WAVE runs a complete independent 8-row
// pipeline. Lane owns 8 units (q = lane + 64k), so each group's 8-9 finals
// land on 8-9 DIFFERENT lanes (~40cy, not serial); z/h1/h2 exchanges are
// wave-private LDS + lgkmcnt(0) -- NO barriers on the chain (wave lockstep).
// Cross-wave coupling reduced to weight staging: per step the block
// double-buffers the step's Wq/W1/Wo rows into LDS (7936 floats, reg-staged
// issue-early/write-late), ONE barrier per step, off-chain.
// 256 thr = 4 waves x 8 rows = 32 rows/block, grid 256 (1 block/CU,
// 1 wave/SIMD -- occupancy ~12% by design; VGPR cap 512 at (256,1), est
// ~280, no spill; tripwire WRITE_SIZE = 6144 KB).
// Finals use unrolled static dispatch (no runtime-indexed register arrays).
// Stale-slot trick kept: slot-8 of Wq (MID) and slots 8/18 of Woq (D) are
// prep-zeroed for 8-wide groups, killing stale h1/h2 slot-8 reads.

typedef float f2 __attribute__((ext_vector_type(2)));

#define Bn 8192
#define Dn 64
#define CTXn 256
#define Hn 512
#define BD (Bn * Dn)

#define WQ_SZ  (64 * 512 * 12)   // 393216
#define WOQ_SZ (64 * 64 * 20)    //  81920
#define WCT_SZ (512 * 256)       // 131072
#define W1P_SZ (64 * 512)        //  32768

// per-step staged row: Wq 6144 | W1 512 | Wo 1280 = 7936 floats = 1984 f4
#define W1OFF 6144
#define WOOFF 6656
#define BUFSZ 7936
#define STG_F4 1984

#define BARRIER() do {                                      \
    asm volatile("s_waitcnt lgkmcnt(0)" ::: "memory");      \
    __builtin_amdgcn_s_barrier();                           \
    asm volatile("" ::: "memory");                          \
  } while (0)

#define WAVE_FENCE() asm volatile("s_waitcnt lgkmcnt(0)" ::: "memory")

// sorted index p -> original hidden unit h, and its degree k.
__device__ __forceinline__ int perm_of(int p, int* degout) {
  int k, t;
  if (p < 72) { k = p / 9 + 1; t = p - (k - 1) * 9; }
  else        { int pp = p - 72; k = pp / 8 + 9; t = pp - (k - 9) * 8; }
  *degout = k;
  return (k - 1) + 63 * t;
}
// original unit h -> sorted index q.
__device__ __forceinline__ int inv_perm(int h) {
  int i = h % 63;
  int t = h / 63;
  int base = (i < 9) ? 9 * i : 72 + 8 * (i - 8);
  return base + t;
}

// ---------------- prep -------------------------------------------------------
// R0 W2-scan:  W2[hq][hp], hp=63e+i -> Wq[i][qs(hq)][e]       (slots 0..8)
// R1 W1-scan:  W1[hq][i]            -> Wq[i][qs(hq)][9]       (legacy, unused)
// R2 Wo-scan:  Wo[o][hp], hp=63p+i  -> Woq[i][o&63][(o>>6)*10+p]
// R3 Wc-scan:  Wc[hq][cc]           -> WcT2[qs(hq)][cc]       (unit-major)
// R4 zero:     Wq[i>=8][q][8], Woq[i>=8][j][8|18]
// R5 biases:   b1p/b2p
// R6 W1-scan2: W1[hq][i]            -> W1p[i][qs(hq)]         (row-major)
#define R0e 262144
#define R1e (R0e + 32768)
#define R2e (R1e + 65536)
#define R3e (R2e + 131072)
#define R4e (R3e + 35840)
#define R5e (R4e + 1024)
#define R6e (R5e + 32768)
__global__ void prep_kernel(const float* __restrict__ W1, const float* __restrict__ Wc,
                            const float* __restrict__ W2, const float* __restrict__ Wo,
                            const float* __restrict__ b1, const float* __restrict__ b2,
                            float* __restrict__ Wq, float* __restrict__ Woq,
                            float* __restrict__ WcT2, float* __restrict__ b1p,
                            float* __restrict__ b2p, float* __restrict__ W1p) {
  int idx = blockIdx.x * 256 + threadIdx.x;
  if (idx < R0e) {                      // W2 scan
    int hq = idx >> 9, hp = idx & 511;
    int i = hp % 63, e = hp / 63;
    Wq[i * 6144 + inv_perm(hq) * 12 + e] = W2[idx];
  } else if (idx < R1e) {               // W1 -> Wq slot 9 (legacy; unused)
    int jj = idx - R0e;
    int hq = jj >> 6, i = jj & 63;
    Wq[i * 6144 + inv_perm(hq) * 12 + 9] = W1[jj];
  } else if (idx < R2e) {               // Wo scan
    int jj = idx - R1e;
    int o = jj >> 9, hp = jj & 511;
    int i = hp % 63, p = hp / 63;
    int j = o & 63, half = o >> 6;
    Woq[i * 1280 + j * 20 + half * 10 + p] = Wo[jj];
  } else if (idx < R3e) {               // Wc scan -> unit-major transpose
    int jj = idx - R2e;
    int hq = jj >> 8, cc = jj & 255;
    WcT2[inv_perm(hq) * 256 + cc] = Wc[jj];
  } else if (idx < R4e) {               // zero 9th slots for 8-wide groups
    int z = idx - R3e;
    if (z < 28672) {                    // Wq[i][q][8], i = 8..63
      int i = 8 + (z >> 9), q = z & 511;
      Wq[i * 6144 + q * 12 + 8] = 0.f;
    } else {                            // Woq[i][j][8 or 18], i = 8..63
      int z2 = z - 28672;
      int i = 8 + (z2 >> 7), r = z2 & 127;
      int j = r & 63, half = r >> 6;
      Woq[i * 1280 + j * 20 + half * 10 + 8] = 0.f;
    }
  } else if (idx < R5e) {               // permuted biases
    int z = idx - R4e;
    if (z < 512) {
      int dq; int hq = perm_of(z, &dq);
      b1p[z] = b1[hq];
    } else {
      int q = z - 512;
      int dq; int hq = perm_of(q, &dq);
      b2p[q] = b2[hq];
    }
  } else if (idx < R6e) {               // W1 -> row-major W1p[i][q]
    int jj = idx - R5e;
    int hq = jj >> 6, i = jj & 63;
    W1p[i * 512 + inv_perm(hq)] = W1[jj];
  }
}

// ---------------- main fused kernel ------------------------------------------
// 256 threads = 4 waves. Wave w owns rows r0 = b0+8w .. +7 (independent
// pipeline). Lane owns units q = lane + 64k (k=0..7) and output cols
// (lane, lane+64) of its wave's 8 rows.
__global__ __launch_bounds__(256, 1)
void made_wi_kernel(
    const float* __restrict__ context, const float* __restrict__ WcT2,
    const float* __restrict__ b1p, const float* __restrict__ Wq,
    const float* __restrict__ Woq, const float* __restrict__ W1p,
    const float* __restrict__ b2p, const float* __restrict__ bo,
    const float* __restrict__ eps, float* __restrict__ out) {
  __shared__ __align__(16) float wbuf[2][BUFSZ];
  __shared__ __align__(16) float ctxL[32 * 264];
  __shared__ __align__(16) float zpub[4][8];
  __shared__ __align__(16) float h1pub[4][9][8];
  __shared__ __align__(16) float h2pub[4][9][8];

  int t = threadIdx.x;
  int w = t >> 6, lane = t & 63;
  int b0 = blockIdx.x * 32;
  int r0 = b0 + 8 * w;

  // ---- stage ctx (32 rows x 256) ----
  #pragma unroll
  for (int m = 0; m < 8; ++m) {
    int i4 = t + 256 * m;
    int r = i4 >> 6, c4 = i4 & 63;
    *(float4*)&ctxL[r * 264 + 4 * c4] =
        *(const float4*)&context[(b0 + r) * CTXn + 4 * c4];
  }
  BARRIER();

  // ---- a1 init + ctx GEMM (unit-major WcT2 rows, b128 loads) ----
  f2 a1[8][4];
  #pragma unroll
  for (int k = 0; k < 8; ++k) {
    float b = b1p[lane + 64 * k];
    #pragma unroll
    for (int rr = 0; rr < 4; ++rr) a1[k][rr] = (f2){b, b};
  }
  {
    #pragma clang loop unroll_count(2)
    for (int c4 = 0; c4 < 64; ++c4) {
      f2 xp0[4], xp1[4], xp2[4], xp3[4];
      #pragma unroll
      for (int rr = 0; rr < 4; ++rr) {
        float4 xa = *(const float4*)&ctxL[(8 * w + 2 * rr) * 264 + 4 * c4];
        float4 xb = *(const float4*)&ctxL[(8 * w + 2 * rr + 1) * 264 + 4 * c4];
        xp0[rr] = (f2){xa.x, xb.x};
        xp1[rr] = (f2){xa.y, xb.y};
        xp2[rr] = (f2){xa.z, xb.z};
        xp3[rr] = (f2){xa.w, xb.w};
      }
      #pragma unroll
      for (int k = 0; k < 8; ++k) {
        float4 wv = *(const float4*)&WcT2[(size_t)(lane + 64 * k) * 256 + 4 * c4];
        f2 w0 = (f2){wv.x, wv.x}, w1 = (f2){wv.y, wv.y};
        f2 w2 = (f2){wv.z, wv.z}, w3 = (f2){wv.w, wv.w};
        #pragma unroll
        for (int rr = 0; rr < 4; ++rr) {
          a1[k][rr] += w0 * xp0[rr];
          a1[k][rr] += w1 * xp1[rr];
          a1[k][rr] += w2 * xp2[rr];
          a1[k][rr] += w3 * xp3[rr];
        }
      }
    }
  }

  f2 a2[8][4];
  #pragma unroll
  for (int k = 0; k < 8; ++k) {
    float b = b2p[lane + 64 * k];
    #pragma unroll
    for (int rr = 0; rr < 4; ++rr) a2[k][rr] = (f2){b, b};
  }
  f2 ocA[4], ocB[4];
  {
    float ba = bo[lane], bb = bo[lane + 64];
    #pragma unroll
    for (int rr = 0; rr < 4; ++rr) { ocA[rr] = (f2){ba, ba}; ocB[rr] = (f2){bb, bb}; }
  }
  f2 ezp[4];
  #pragma unroll
  for (int rr = 0; rr < 4; ++rr)
    ezp[rr] = (f2){eps[(r0 + 2 * rr) * Dn + lane],
                   eps[(r0 + 2 * rr + 1) * Dn + lane]};

  // ---- stage step-0 weights into wbuf[0] ----
  {
    float4 st[8];
    #pragma unroll
    for (int m = 0; m < 8; ++m) {
      int idx = t + 256 * m;
      if (m < 7 || t < STG_F4 - 1792) {
        const float* src = (idx < 1536) ? Wq + (size_t)idx * 4
                         : (idx < 1664) ? W1p + (size_t)(idx - 1536) * 4
                                        : Woq + (size_t)(idx - 1664) * 4;
        st[m] = *(const float4*)src;
      }
    }
    #pragma unroll
    for (int m = 0; m < 8; ++m) {
      int idx = t + 256 * m;
      if (m < 7 || t < STG_F4 - 1792)
        *(float4*)&wbuf[0][idx * 4] = st[m];
    }
  }
  BARRIER();

  // ---- step loop: ONE barrier/step; chain is wave-internal ----
  #pragma clang loop unroll(disable)
  for (int S = 0; S < Dn; ++S) {
    int buf = S & 1, nb = buf ^ 1;
    const float* WqL = &wbuf[buf][0];
    const float* W1L = &wbuf[buf][W1OFF];
    const float* WoL = &wbuf[buf][WOOFF];

    // staging loads for step S+1 (issue early; write late)
    float4 st[8];
    bool doStage = (S < 63);
    if (doStage) {
      #pragma unroll
      for (int m = 0; m < 8; ++m) {
        int idx = t + 256 * m;
        if (m < 7 || t < STG_F4 - 1792) {
          const float* src =
              (idx < 1536) ? Wq + (size_t)(S + 1) * 6144 + (size_t)idx * 4
            : (idx < 1664) ? W1p + (size_t)(S + 1) * 512 + (size_t)(idx - 1536) * 4
                           : Woq + (size_t)(S + 1) * 1280 + (size_t)(idx - 1664) * 4;
          st[m] = *(const float4*)src;
        }
      }
    }

    // E: lane S finalizes cols (S, S+64) for its wave's 8 rows
    if (lane == S) {
      float4 zlo, zhi;
      #pragma unroll
      for (int rr = 0; rr < 4; ++rr) {
        f2 pre = ocB[rr];
        float sx = fmaxf(pre.x, 0.f) + __logf(1.f + __expf(-fabsf(pre.x)));
        float sy = fmaxf(pre.y, 0.f) + __logf(1.f + __expf(-fabsf(pre.y)));
        f2 sc = (f2){sx, sy};
        f2 z = ocA[rr] + sc * ezp[rr];
        out[(r0 + 2 * rr) * Dn + S] = z.x;
        out[(r0 + 2 * rr + 1) * Dn + S] = z.y;
        out[BD + (r0 + 2 * rr) * Dn + S] = ocA[rr].x;
        out[BD + (r0 + 2 * rr + 1) * Dn + S] = ocA[rr].y;
        out[2 * BD + (r0 + 2 * rr) * Dn + S] = sc.x;
        out[2 * BD + (r0 + 2 * rr + 1) * Dn + S] = sc.y;
        if (rr == 0) { zlo.x = z.x; zlo.y = z.y; }
        if (rr == 1) { zlo.z = z.x; zlo.w = z.y; }
        if (rr == 2) { zhi.x = z.x; zhi.y = z.y; }
        if (rr == 3) { zhi.z = z.x; zhi.w = z.y; }
      }
      *(float4*)&zpub[w][0] = zlo;
      *(float4*)&zpub[w][4] = zhi;
    }
    WAVE_FENCE();                               // z_S visible (wave-internal)

    bool fin = (S <= 62);
    if (fin) {
      int sb = (S < 8) ? 9 * S : 8 * S + 8;
      int e = (S < 8) ? 9 : 8;
      int jj = (lane - sb) & 63;
      bool own = (jj < e);
      int qown = sb + jj;

      // ---- FA bulk: a1 += W1[S] * z_S ----
      float4 z0 = *(const float4*)&zpub[w][0];
      float4 z1 = *(const float4*)&zpub[w][4];
      f2 zz[4] = {(f2){z0.x, z0.y}, (f2){z0.z, z0.w},
                  (f2){z1.x, z1.y}, (f2){z1.z, z1.w}};
      #pragma unroll
      for (int k = 0; k < 8; ++k) {
        float wv = W1L[lane + 64 * k];
        f2 ww = (f2){wv, wv};
        #pragma unroll
        for (int rr = 0; rr < 4; ++rr) a1[k][rr] += ww * zz[rr];
      }
      // ---- h1 final (group-S owner lanes; static dispatch) ----
      if (own) {
        #pragma unroll
        for (int k = 0; k < 8; ++k) {
          if ((qown >> 6) == k) {
            float4 h0 = {fmaxf(a1[k][0].x, 0.f), fmaxf(a1[k][0].y, 0.f),
                         fmaxf(a1[k][1].x, 0.f), fmaxf(a1[k][1].y, 0.f)};
            float4 h1_ = {fmaxf(a1[k][2].x, 0.f), fmaxf(a1[k][2].y, 0.f),
                          fmaxf(a1[k][3].x, 0.f), fmaxf(a1[k][3].y, 0.f)};
            *(float4*)&h1pub[w][jj][0] = h0;
            *(float4*)&h1pub[w][jj][4] = h1_;
          }
        }
      }
      WAVE_FENCE();                             // h1_S visible

      // ---- MID bulk: a2 += W2[:, group S] . h1_S ----
      float4 h1a[9], h1b[9];
      #pragma unroll
      for (int p = 0; p < 9; ++p) {
        h1a[p] = *(const float4*)&h1pub[w][p][0];
        h1b[p] = *(const float4*)&h1pub[w][p][4];
      }
      #pragma unroll
      for (int k = 0; k < 8; ++k) {
        const float* wq = WqL + (lane + 64 * k) * 12;
        float4 wA = *(const float4*)wq;
        float4 wB = *(const float4*)(wq + 4);
        float4 wC = *(const float4*)(wq + 8);
        float wv[9] = {wA.x, wA.y, wA.z, wA.w, wB.x, wB.y, wB.z, wB.w, wC.x};
        #pragma unroll
        for (int p = 0; p < 9; ++p) {
          f2 ww = (f2){wv[p], wv[p]};
          a2[k][0] += ww * (f2){h1a[p].x, h1a[p].y};
          a2[k][1] += ww * (f2){h1a[p].z, h1a[p].w};
          a2[k][2] += ww * (f2){h1b[p].x, h1b[p].y};
          a2[k][3] += ww * (f2){h1b[p].z, h1b[p].w};
        }
      }
      // ---- h2 final ----
      if (own) {
        #pragma unroll
        for (int k = 0; k < 8; ++k) {
          if ((qown >> 6) == k) {
            float4 h0 = {fmaxf(a2[k][0].x, 0.f), fmaxf(a2[k][0].y, 0.f),
                         fmaxf(a2[k][1].x, 0.f), fmaxf(a2[k][1].y, 0.f)};
            float4 h1_ = {fmaxf(a2[k][2].x, 0.f), fmaxf(a2[k][2].y, 0.f),
                          fmaxf(a2[k][3].x, 0.f), fmaxf(a2[k][3].y, 0.f)};
            *(float4*)&h2pub[w][jj][0] = h0;
            *(float4*)&h2pub[w][jj][4] = h1_;
          }
        }
      }
      WAVE_FENCE();                             // h2_S visible

      // ---- D: oc += Wo[:, group S] . h2_S (cols lane, lane+64) ----
      const float* wo = WoL + lane * 20;
      float4 W0 = *(const float4*)wo;
      float4 W1v = *(const float4*)(wo + 4);
      float4 W2v = *(const float4*)(wo + 8);
      float4 W3v = *(const float4*)(wo + 12);
      float4 W4v = *(const float4*)(wo + 16);
      float wa[9] = {W0.x, W0.y, W0.z, W0.w, W1v.x, W1v.y, W1v.z, W1v.w, W2v.x};
      float wb[9] = {W2v.z, W2v.w, W3v.x, W3v.y, W3v.z, W3v.w, W4v.x, W4v.y, W4v.z};
      #pragma unroll
      for (int p = 0; p < 9; ++p) {
        float4 ha = *(const float4*)&h2pub[w][p][0];
        float4 hb = *(const float4*)&h2pub[w][p][4];
        f2 h01 = (f2){ha.x, ha.y}, h23 = (f2){ha.z, ha.w};
        f2 h45 = (f2){hb.x, hb.y}, h67 = (f2){hb.z, hb.w};
        f2 va = (f2){wa[p], wa[p]}, vb = (f2){wb[p], wb[p]};
        ocA[0] += va * h01; ocA[1] += va * h23;
        ocA[2] += va * h45; ocA[3] += va * h67;
        ocB[0] += vb * h01; ocB[1] += vb * h23;
        ocB[2] += vb * h45; ocB[3] += vb * h67;
      }
    }

    // staging writes (compiler inserts vmcnt waits on st deps)
    if (doStage) {
      #pragma unroll
      for (int m = 0; m < 8; ++m) {
        int idx = t + 256 * m;
        if (m < 7 || t < STG_F4 - 1792)
          *(float4*)&wbuf[nb][idx * 4] = st[m];
      }
    }
    BARRIER();                                  // buffer swap (off-chain)
  }
}

extern "C" void kernel_launch(void* const* d_in, const int* in_sizes, int n_in,
                              void* d_out, int out_size, void* d_ws, size_t ws_size,
                              hipStream_t stream) {
  const float* context = (const float*)d_in[0];
  const float* eps     = (const float*)d_in[1];
  const float* W1      = (const float*)d_in[2];
  const float* b1      = (const float*)d_in[3];
  const float* Wc      = (const float*)d_in[4];
  const float* W2      = (const float*)d_in[5];
  const float* b2      = (const float*)d_in[6];
  const float* Wo      = (const float*)d_in[7];
  const float* bo      = (const float*)d_in[8];
  float* out = (float*)d_out;

  float* ws   = (float*)d_ws;
  float* Wq   = ws;                        // 393216 floats
  float* Woq  = Wq + WQ_SZ;                //  81920
  float* WcT2 = Woq + WOQ_SZ;              // 131072
  float* b1p  = WcT2 + WCT_SZ;             //    512
  float* b2p  = b1p + 512;                 //    512
  float* W1p  = b2p + 512;                 //  32768
  // total ws use: ~2.56 MB (L2-resident)

  prep_kernel<<<(R6e + 255) / 256, 256, 0, stream>>>(
      W1, Wc, W2, Wo, b1, b2, Wq, Woq, WcT2, b1p, b2p, W1p);
  made_wi_kernel<<<Bn / 32, 256, 0, stream>>>(context, WcT2, b1p, Wq, Woq,
                                              W1p, b2p, bo, eps, out);
}

// Round 10
// 291.562 us; speedup vs baseline: 1.5325x; 1.5325x over previous
//
#include <hip/hip_runtime.h>
#include <math.h>

// MADE autoregressive sampler, v20: wave-private pipeline, weights global.
// B=8192, D=64, CTX=256, H=512. Units sorted by degree (mh = h%63+1).
// v19 failed (391us) from two confounds: LDS-staged weights at stride-12/20
// (bank conflicts 774K -> 4.7e7) and 1 wave/SIMD (no TLP). The fix keeps the
// untested core idea -- wave = independent pipeline, ZERO barriers in the
// 64-step loop -- but takes weights global->register (v16's proven pattern;
// thread-private data does not belong in LDS) and keeps only z/h1/h2 in
// wave-private LDS with broadcast (wave-uniform) reads + lgkmcnt fences.
// Config: 256 thr = 4 waves x 4 rows (Rn=16), grid 512 = 2 blocks/CU =
// 2 waves/SIMD (same TLP as v16). Per-thread arithmetic identical to v16
// (FA 16 + MID 144 + D 36 pk-fma/step) -> clean A/B on sync structure alone.
// ctx GEMM stays block-cooperative (v16 verbatim, 4x less L2 than per-wave),
// handed to wave-private layout via one-time stride-17 LDS transpose
// (conflict-free), 2 barriers total outside the loop.
// Known risk: 8 waves/CU re-read the same 31.7KB/step weights; L1 (32KB)
// should absorb (all waves near-lockstep); L2-bound fallback ~150us.
// Spill tripwire: WRITE_SIZE must stay 6144 KB. VGPR est 200-240 (cap 256).

typedef float f2 __attribute__((ext_vector_type(2)));

#define Bn 8192
#define Dn 64
#define CTXn 256
#define Hn 512
#define Rn 16
#define BD (Bn * Dn)

#define WQ_SZ  (64 * 512 * 12)   // 393216
#define WOQ_SZ (64 * 64 * 20)    //  81920
#define WCP_SZ (CTXn * Hn)       // 131072
#define W1P_SZ (64 * 512)        //  32768

#define BARRIER() do {                                      \
    asm volatile("s_waitcnt lgkmcnt(0)" ::: "memory");      \
    __builtin_amdgcn_s_barrier();                           \
    asm volatile("" ::: "memory");                          \
  } while (0)

// wave-internal LDS fence: drains this wave's LDS ops; wave lockstep makes
// the written values visible to all lanes. Global loads (vmcnt) unaffected.
#define WAVE_FENCE() asm volatile("s_waitcnt lgkmcnt(0)" ::: "memory")

// sorted index p -> original hidden unit h, and its degree k.
__device__ __forceinline__ int perm_of(int p, int* degout) {
  int k, t;
  if (p < 72) { k = p / 9 + 1; t = p - (k - 1) * 9; }
  else        { int pp = p - 72; k = pp / 8 + 9; t = pp - (k - 9) * 8; }
  *degout = k;
  return (k - 1) + 63 * t;
}
// original unit h -> sorted index q.
__device__ __forceinline__ int inv_perm(int h) {
  int i = h % 63;
  int t = h / 63;
  int base = (i < 9) ? 9 * i : 72 + 8 * (i - 8);
  return base + t;
}

// ---------------- prep -------------------------------------------------------
// R0 W2-scan:  W2[hq][hp], hp=63e+i -> Wq[i][qs(hq)][e]
// R1 W1-scan:  W1[hq][i]            -> Wq[i][qs(hq)][9]   (unused; harmless)
// R2 Wo-scan:  Wo[o][hp], hp=63p+i  -> Woq[i][o&63][(o>>6)*10+p]
// R3 Wc-scan:  Wc[hq][cc]           -> WcpT[cc][pairslot(qs(hq))] (v16 layout)
// R4 zero:     Wq[i>=8][q][8], Woq[i>=8][j][8|18]
// R5 biases:   b1p/b2p
// R6 W1-scan2: W1[hq][i]            -> W1p[i][qs(hq)]  (row-major, FA loads)
#define R0e 262144
#define R1e (R0e + 32768)
#define R2e (R1e + 65536)
#define R3e (R2e + 131072)
#define R4e (R3e + 35840)
#define R5e (R4e + 1024)
#define R6e (R5e + 32768)
__global__ void prep_kernel(const float* __restrict__ W1, const float* __restrict__ Wc,
                            const float* __restrict__ W2, const float* __restrict__ Wo,
                            const float* __restrict__ b1, const float* __restrict__ b2,
                            float* __restrict__ Wq, float* __restrict__ Woq,
                            float* __restrict__ WcpT, float* __restrict__ b1p,
                            float* __restrict__ b2p, float* __restrict__ W1p) {
  int idx = blockIdx.x * 256 + threadIdx.x;
  if (idx < R0e) {                      // W2 scan
    int hq = idx >> 9, hp = idx & 511;
    int i = hp % 63, e = hp / 63;
    Wq[i * 6144 + inv_perm(hq) * 12 + e] = W2[idx];
  } else if (idx < R1e) {               // W1 -> Wq slot 9 (legacy; unused)
    int jj = idx - R0e;
    int hq = jj >> 6, i = jj & 63;
    Wq[i * 6144 + inv_perm(hq) * 12 + 9] = W1[jj];
  } else if (idx < R2e) {               // Wo scan
    int jj = idx - R1e;
    int o = jj >> 9, hp = jj & 511;
    int i = hp % 63, p = hp / 63;
    int j = o & 63, half = o >> 6;
    Woq[i * 1280 + j * 20 + half * 10 + p] = Wo[jj];
  } else if (idx < R3e) {               // Wc scan (pair-interleaved, v16)
    int jj = idx - R2e;
    int hq = jj >> 8, cc = jj & 255;
    int p = inv_perm(hq);
    int slot = (p < 256) ? (2 * p) : (2 * (p - 256) + 1);
    WcpT[cc * 512 + slot] = Wc[jj];
  } else if (idx < R4e) {               // zero 9th slots for 8-wide groups
    int z = idx - R3e;
    if (z < 28672) {                    // Wq[i][q][8], i = 8..63
      int i = 8 + (z >> 9), q = z & 511;
      Wq[i * 6144 + q * 12 + 8] = 0.f;
    } else {                            // Woq[i][j][8 or 18], i = 8..63
      int z2 = z - 28672;
      int i = 8 + (z2 >> 7), r = z2 & 127;
      int j = r & 63, half = r >> 6;
      Woq[i * 1280 + j * 20 + half * 10 + 8] = 0.f;
    }
  } else if (idx < R5e) {               // permuted biases
    int z = idx - R4e;
    if (z < 512) {
      int dq; int hq = perm_of(z, &dq);
      b1p[z] = b1[hq];
    } else {
      int q = z - 512;
      int dq; int hq = perm_of(q, &dq);
      b2p[q] = b2[hq];
    }
  } else if (idx < R6e) {               // W1 -> row-major W1p[i][q]
    int jj = idx - R5e;
    int hq = jj >> 6, i = jj & 63;
    W1p[i * 512 + inv_perm(hq)] = W1[jj];
  }
}

// ---------------- main fused kernel ------------------------------------------
// 256 threads = 4 waves. Wave w: rows r0 = b0+4w .. +3 (independent pipeline).
// Lane owns units q = lane + 64k (k=0..7) and output cols (lane, lane+64).
__global__ __launch_bounds__(256, 2)
void made_wp_kernel(
    const float* __restrict__ context, const float* __restrict__ WcpT,
    const float* __restrict__ b1p, const float* __restrict__ Wq,
    const float* __restrict__ Woq, const float* __restrict__ W1p,
    const float* __restrict__ b2p, const float* __restrict__ bo,
    const float* __restrict__ eps, float* __restrict__ out) {
  __shared__ __align__(16) float ctxR[Rn][264];
  __shared__ __align__(16) float a1x[512][17];    // transfer, stride-17 pad
  __shared__ __align__(16) float zpub[4][4];
  __shared__ __align__(16) float h1pub[4][9][4];
  __shared__ __align__(16) float h2pub[4][9][4];

  int t = threadIdx.x;
  int w = t >> 6, lane = t & 63;
  int b0 = blockIdx.x * Rn;
  int r0 = b0 + 4 * w;

  // ---- stage ctx (16 rows x 256) ----
  #pragma unroll
  for (int r = 0; r < Rn; ++r)
    ctxR[r][t] = context[(b0 + r) * CTXn + t];
  BARRIER();

  // ---- ctx GEMM, block-cooperative (v16 verbatim): thread t owns units
  //      (t, t+256) x 16 rows ----
  f2 accu[16];
  {
    f2 bias = (f2){b1p[t], b1p[t + 256]};
    #pragma unroll
    for (int r = 0; r < 16; ++r) accu[r] = bias;
  }
  {
    const float* wc = WcpT + 2 * t;
    #pragma clang loop unroll(disable)
    for (int c4 = 0; c4 < CTXn / 4; ++c4) {
      f2 wv0 = *(const f2*)&wc[0];
      f2 wv1 = *(const f2*)&wc[Hn];
      f2 wv2 = *(const f2*)&wc[2 * Hn];
      f2 wv3 = *(const f2*)&wc[3 * Hn];
      wc += 4 * Hn;
      #pragma unroll
      for (int hf = 0; hf < 2; ++hf) {
        float4 x[8];
        #pragma unroll
        for (int r = 0; r < 8; ++r) x[r] = *(const float4*)&ctxR[8 * hf + r][4 * c4];
        #pragma unroll
        for (int r = 0; r < 8; ++r) {
          accu[8 * hf + r] += (f2){x[r].x, x[r].x} * wv0;
          accu[8 * hf + r] += (f2){x[r].y, x[r].y} * wv1;
          accu[8 * hf + r] += (f2){x[r].z, x[r].z} * wv2;
          accu[8 * hf + r] += (f2){x[r].w, x[r].w} * wv3;
        }
      }
    }
  }

  // ---- transfer accumulators to wave-private layout via LDS ----
  #pragma unroll
  for (int r = 0; r < 16; ++r) {
    a1x[t][r] = accu[r].x;            // unit t, row r      (stride 17: no conflict)
    a1x[t + 256][r] = accu[r].y;      // unit t+256, row r
  }
  BARRIER();

  // a1[k] = f2 row-pairs (rows 4w..4w+3) for unit lane+64k
  f2 a1[8][2];
  #pragma unroll
  for (int k = 0; k < 8; ++k) {
    int q = lane + 64 * k;
    a1[k][0] = (f2){a1x[q][4 * w + 0], a1x[q][4 * w + 1]};
    a1[k][1] = (f2){a1x[q][4 * w + 2], a1x[q][4 * w + 3]};
  }

  f2 a2[8][2];
  #pragma unroll
  for (int k = 0; k < 8; ++k) {
    float b = b2p[lane + 64 * k];
    a2[k][0] = (f2){b, b};
    a2[k][1] = (f2){b, b};
  }
  f2 ocA[2], ocB[2];
  {
    float ba = bo[lane], bb = bo[lane + 64];
    ocA[0] = ocA[1] = (f2){ba, ba};
    ocB[0] = ocB[1] = (f2){bb, bb};
  }
  f2 ez[2];
  ez[0] = (f2){eps[(r0 + 0) * Dn + lane], eps[(r0 + 1) * Dn + lane]};
  ez[1] = (f2){eps[(r0 + 2) * Dn + lane], eps[(r0 + 3) * Dn + lane]};

  // ---- step loop: ZERO barriers; chain entirely wave-internal ----
  #pragma clang loop unroll(disable)
  for (int S = 0; S < Dn; ++S) {
    bool fin = (S <= 62);

    // issue this step's weight loads (global->reg; consumed 150-500cy later)
    float4 wqv[8][3];
    float w1v[8];
    if (fin) {
      const float* wbase = Wq + (size_t)S * 6144;
      const float* w1base = W1p + (size_t)S * 512;
      #pragma unroll
      for (int k = 0; k < 8; ++k) {
        const float4* pq = (const float4*)(wbase + (size_t)(lane + 64 * k) * 12);
        wqv[k][0] = pq[0]; wqv[k][1] = pq[1]; wqv[k][2] = pq[2];
        w1v[k] = w1base[lane + 64 * k];
      }
    }

    // E: lane S finalizes cols (S, S+64) for its wave's 4 rows; stream out
    if (lane == S) {
      f2 zv0, zv1;
      #pragma unroll
      for (int rr = 0; rr < 2; ++rr) {
        f2 pre = ocB[rr];
        float sx = fmaxf(pre.x, 0.f) + __logf(1.f + __expf(-fabsf(pre.x)));
        float sy = fmaxf(pre.y, 0.f) + __logf(1.f + __expf(-fabsf(pre.y)));
        f2 sc = (f2){sx, sy};
        f2 z = ocA[rr] + sc * ez[rr];
        out[(r0 + 2 * rr) * Dn + S] = z.x;
        out[(r0 + 2 * rr + 1) * Dn + S] = z.y;
        out[BD + (r0 + 2 * rr) * Dn + S] = ocA[rr].x;
        out[BD + (r0 + 2 * rr + 1) * Dn + S] = ocA[rr].y;
        out[2 * BD + (r0 + 2 * rr) * Dn + S] = sc.x;
        out[2 * BD + (r0 + 2 * rr + 1) * Dn + S] = sc.y;
        if (rr == 0) zv0 = z; else zv1 = z;
      }
      *(float4*)&zpub[w][0] = (float4){zv0.x, zv0.y, zv1.x, zv1.y};
    }
    WAVE_FENCE();                               // z_S visible (wave-internal)

    if (fin) {
      int sb = (S < 8) ? 9 * S : 8 * S + 8;
      int e = (S < 8) ? 9 : 8;
      int jj = (lane - sb) & 63;
      bool own = (jj < e);
      int qown = sb + jj;

      // FA: a1 += W1[:,S] * z_S
      float4 zq = *(const float4*)&zpub[w][0];
      f2 zz0 = (f2){zq.x, zq.y}, zz1 = (f2){zq.z, zq.w};
      #pragma unroll
      for (int k = 0; k < 8; ++k) {
        f2 ww = (f2){w1v[k], w1v[k]};
        a1[k][0] += ww * zz0;
        a1[k][1] += ww * zz1;
      }
      // Woq loads for D (covered by MID ~400cy)
      const float4* wo = (const float4*)(Woq + (size_t)S * 1280 + (size_t)lane * 20);
      float4 wo0 = wo[0], wo1 = wo[1], wo2 = wo[2], wo3 = wo[3], wo4 = wo[4];

      // h1 final (group-S owner lanes; static k dispatch)
      if (own) {
        #pragma unroll
        for (int k = 0; k < 8; ++k) {
          if ((qown >> 6) == k) {
            *(float4*)&h1pub[w][jj][0] =
                (float4){fmaxf(a1[k][0].x, 0.f), fmaxf(a1[k][0].y, 0.f),
                         fmaxf(a1[k][1].x, 0.f), fmaxf(a1[k][1].y, 0.f)};
          }
        }
      }
      WAVE_FENCE();                             // h1_S visible

      // MID: a2 += W2[:, group S] . h1_S  (p-outer: one broadcast read/p)
      #pragma unroll
      for (int p = 0; p < 9; ++p) {
        float4 hv = *(const float4*)&h1pub[w][p][0];
        f2 h01 = (f2){hv.x, hv.y}, h23 = (f2){hv.z, hv.w};
        #pragma unroll
        for (int k = 0; k < 8; ++k) {
          float wsc = (p == 0) ? wqv[k][0].x : (p == 1) ? wqv[k][0].y
                    : (p == 2) ? wqv[k][0].z : (p == 3) ? wqv[k][0].w
                    : (p == 4) ? wqv[k][1].x : (p == 5) ? wqv[k][1].y
                    : (p == 6) ? wqv[k][1].z : (p == 7) ? wqv[k][1].w
                               : wqv[k][2].x;
          f2 ww = (f2){wsc, wsc};
          a2[k][0] += ww * h01;
          a2[k][1] += ww * h23;
        }
      }
      // h2 final
      if (own) {
        #pragma unroll
        for (int k = 0; k < 8; ++k) {
          if ((qown >> 6) == k) {
            *(float4*)&h2pub[w][jj][0] =
                (float4){fmaxf(a2[k][0].x, 0.f), fmaxf(a2[k][0].y, 0.f),
                         fmaxf(a2[k][1].x, 0.f), fmaxf(a2[k][1].y, 0.f)};
          }
        }
      }
      WAVE_FENCE();                             // h2_S visible

      // D: oc += Wo[:, group S] . h2_S  (slot 8 prep-zeroed for S>=8)
      {
        float wa[9] = {wo0.x, wo0.y, wo0.z, wo0.w, wo1.x, wo1.y, wo1.z, wo1.w, wo2.x};
        float wb[9] = {wo2.z, wo2.w, wo3.x, wo3.y, wo3.z, wo3.w, wo4.x, wo4.y, wo4.z};
        #pragma unroll
        for (int p = 0; p < 9; ++p) {
          float4 hv = *(const float4*)&h2pub[w][p][0];
          f2 h01 = (f2){hv.x, hv.y}, h23 = (f2){hv.z, hv.w};
          f2 va = (f2){wa[p], wa[p]}, vb = (f2){wb[p], wb[p]};
          ocA[0] += va * h01; ocA[1] += va * h23;
          ocB[0] += vb * h01; ocB[1] += vb * h23;
        }
      }
    }
  }
  // outputs fully streamed in E; no epilogue
}

extern "C" void kernel_launch(void* const* d_in, const int* in_sizes, int n_in,
                              void* d_out, int out_size, void* d_ws, size_t ws_size,
                              hipStream_t stream) {
  const float* context = (const float*)d_in[0];
  const float* eps     = (const float*)d_in[1];
  const float* W1      = (const float*)d_in[2];
  const float* b1      = (const float*)d_in[3];
  const float* Wc      = (const float*)d_in[4];
  const float* W2      = (const float*)d_in[5];
  const float* b2      = (const float*)d_in[6];
  const float* Wo      = (const float*)d_in[7];
  const float* bo      = (const float*)d_in[8];
  float* out = (float*)d_out;

  float* ws   = (float*)d_ws;
  float* Wq   = ws;                        // 393216 floats
  float* Woq  = Wq + WQ_SZ;                //  81920
  float* WcpT = Woq + WOQ_SZ;              // 131072
  float* b1p  = WcpT + WCP_SZ;             //    512
  float* b2p  = b1p + 512;                 //    512
  float* W1p  = b2p + 512;                 //  32768
  // total ws use: ~2.56 MB (L2-resident)

  prep_kernel<<<(R6e + 255) / 256, 256, 0, stream>>>(
      W1, Wc, W2, Wo, b1, b2, Wq, Woq, WcpT, b1p, b2p, W1p);
  made_wp_kernel<<<Bn / Rn, 256, 0, stream>>>(context, WcpT, b1p, Wq, Woq,
                                              W1p, b2p, bo, eps, out);
}

// Round 11
// 243.225 us; speedup vs baseline: 1.8370x; 1.1987x over previous
//
#include <hip/hip_runtime.h>
#include <math.h>

// MADE autoregressive sampler, incremental-by-degree, v21 = v16 + prefetch.
// B=8192, D=64, CTX=256, H=512. Units sorted by degree (mh = h%63+1).
// Ledger: v14 185 / v15 310 / v16 180 / v17 250 / v18 208 / v19 391 / v20 245.
// v20 (zero loop barriers, zero conflicts, no spill) at 245 falsifies the
// chain-sync hypothesis; v16 remains best. Issue-equiv (VALUBusy x dur) is
// ~72-96us across all structures -> redistribute stalls, don't add work.
// v21: keep v16 byte-identical arithmetic/barriers/publishes; move ALL weight
// loads off the consume path via one-step register rotation:
//   prologue: load Wq[0] (6 b128) + Woq[0] (5 b128) into C/WB regs;
//   phase B of step S: issue Wq[S+1]/Woq[S+1] into P/PW regs (window =
//   MID + bar3 + D + E + bar1 ~ 1000cy); rotate at loop bottom.
// This is v13's idea, which spilled at the 64-VGPR clamp; v16 runs 100 VGPR
// under a 256 cap, so +44 live VGPRs is now safe. Spill tripwire: WRITE_SIZE
// must stay 6144 KB.

typedef float f2 __attribute__((ext_vector_type(2)));

#define Bn 8192
#define Dn 64
#define CTXn 256
#define Hn 512
#define Rn 16
#define BD (Bn * Dn)

#define WQ_SZ  (64 * 512 * 12)   // 393216
#define WOQ_SZ (64 * 64 * 20)    //  81920
#define WCP_SZ (CTXn * Hn)       // 131072

// lgkm-only block barrier: drains LDS ops, leaves global loads in flight.
#define BARRIER() do {                                      \
    asm volatile("s_waitcnt lgkmcnt(0)" ::: "memory");      \
    __builtin_amdgcn_s_barrier();                           \
    asm volatile("" ::: "memory");                          \
  } while (0)

// sorted index p -> original hidden unit h, and its degree k.
__device__ __forceinline__ int perm_of(int p, int* degout) {
  int k, t;
  if (p < 72) { k = p / 9 + 1; t = p - (k - 1) * 9; }
  else        { int pp = p - 72; k = pp / 8 + 9; t = pp - (k - 9) * 8; }
  *degout = k;
  return (k - 1) + 63 * t;
}
// original unit h -> sorted index q.
__device__ __forceinline__ int inv_perm(int h) {
  int i = h % 63;            // = degree-1
  int t = h / 63;
  int base = (i < 9) ? 9 * i : 72 + 8 * (i - 8);   // S_of(i+1)
  return base + t;
}

// ---------------- prep: scan-order, coalesced reads (v16 unchanged) ---------
#define R0e 262144
#define R1e (R0e + 32768)
#define R2e (R1e + 65536)
#define R3e (R2e + 131072)
#define R4e (R3e + 35840)
#define R5e (R4e + 1024)
__global__ void prep_kernel(const float* __restrict__ W1, const float* __restrict__ Wc,
                            const float* __restrict__ W2, const float* __restrict__ Wo,
                            const float* __restrict__ b1, const float* __restrict__ b2,
                            float* __restrict__ Wq, float* __restrict__ Woq,
                            float* __restrict__ WcpT, float* __restrict__ b1p,
                            float* __restrict__ b2p) {
  int idx = blockIdx.x * 256 + threadIdx.x;
  if (idx < R0e) {                      // W2 scan (coalesced read)
    int hq = idx >> 9, hp = idx & 511;
    int i = hp % 63, e = hp / 63;
    Wq[i * 6144 + inv_perm(hq) * 12 + e] = W2[idx];
  } else if (idx < R1e) {               // W1 scan
    int jj = idx - R0e;
    int hq = jj >> 6, i = jj & 63;
    Wq[i * 6144 + inv_perm(hq) * 12 + 9] = W1[jj];
  } else if (idx < R2e) {               // Wo scan
    int jj = idx - R1e;
    int o = jj >> 9, hp = jj & 511;
    int i = hp % 63, p = hp / 63;
    int j = o & 63, half = o >> 6;
    Woq[i * 1280 + j * 20 + half * 10 + p] = Wo[jj];
  } else if (idx < R3e) {               // Wc scan (pair-interleaved layout)
    int jj = idx - R2e;
    int hq = jj >> 8, cc = jj & 255;
    int p = inv_perm(hq);
    int slot = (p < 256) ? (2 * p) : (2 * (p - 256) + 1);
    WcpT[cc * 512 + slot] = Wc[jj];
  } else if (idx < R4e) {               // zero the 9th slots for 8-wide groups
    int z = idx - R3e;
    if (z < 28672) {                    // Wq[i][q][8], i = 8..63
      int i = 8 + (z >> 9), q = z & 511;
      Wq[i * 6144 + q * 12 + 8] = 0.f;
    } else {                            // Woq[i][j][8 or 18], i = 8..63
      int z2 = z - 28672;
      int i = 8 + (z2 >> 7), r = z2 & 127;
      int j = r & 63, half = r >> 6;
      Woq[i * 1280 + j * 20 + half * 10 + 8] = 0.f;
    }
  } else if (idx < R5e) {               // permuted biases
    int z = idx - R4e;
    if (z < 512) {
      int dq; int hq = perm_of(z, &dq);
      b1p[z] = b1[hq];
    } else {
      int q = z - 512;
      int dq; int hq = perm_of(q, &dq);
      b2p[q] = b2[hq];
    }
  }
}

// ---------------- main fused kernel ------------------------------------------
// 256 threads = 4 waves; wave rp owns rows 4rp..4rp+3; thread (rp,l) owns
// units q0=t, q1=t+256 and output cols (l, l+64) of its wave's 4 rows.
__global__ __launch_bounds__(256, 2)
void made_pk_kernel(
    const float* __restrict__ context, const float* __restrict__ WcpT,
    const float* __restrict__ b1p,
    const float* __restrict__ Wq, const float* __restrict__ Woq,
    const float* __restrict__ b2p, const float* __restrict__ bo,
    const float* __restrict__ eps, float* __restrict__ out) {
  __shared__ __align__(16) float ctxR[Rn][264];
  __shared__ __align__(16) float zcur[16];
  __shared__ __align__(16) float h1g[9][16];
  __shared__ __align__(16) float h2g[9][16];

  int t = threadIdx.x;
  int b0 = blockIdx.x * Rn;
  int rp = t >> 6, l = t & 63;
  int q0 = t, q1 = t + 256;              // owned sorted units

  int g0 = ((q0 < 72) ? q0 / 9 + 1 : (q0 - 72) / 8 + 9) - 1;   // finalize steps
  int g1 = ((q1 - 72) / 8 + 9) - 1;
  int qm = t | 63;                        // wave-uniform max index
  int gm0s = __builtin_amdgcn_readfirstlane(
      ((qm < 72) ? qm / 9 + 1 : (qm - 72) / 8 + 9) - 1);
  int gm1s = __builtin_amdgcn_readfirstlane(((qm + 256 - 72) / 8 + 9) - 1);

  // ---- stage ctx (16 rows) ----
  #pragma unroll
  for (int r = 0; r < Rn; ++r)
    ctxR[r][t] = context[(b0 + r) * CTXn + t];
  BARRIER();

  // ---- ctx GEMM, unit-pair packed (v16) ----
  f2 accu[16];
  {
    f2 bias = (f2){b1p[q0], b1p[q1]};
    #pragma unroll
    for (int r = 0; r < 16; ++r) accu[r] = bias;
  }
  {
    const float* wc = WcpT + 2 * t;      // pair base for this thread
    #pragma clang loop unroll(disable)
    for (int c4 = 0; c4 < CTXn / 4; ++c4) {
      f2 wv0 = *(const f2*)&wc[0];
      f2 wv1 = *(const f2*)&wc[Hn];
      f2 wv2 = *(const f2*)&wc[2 * Hn];
      f2 wv3 = *(const f2*)&wc[3 * Hn];
      wc += 4 * Hn;
      #pragma unroll
      for (int hf = 0; hf < 2; ++hf) {   // row halves: 0-7, 8-15
        float4 x[8];
        #pragma unroll
        for (int r = 0; r < 8; ++r) x[r] = *(const float4*)&ctxR[8 * hf + r][4 * c4];
        #pragma unroll
        for (int r = 0; r < 8; ++r) {
          accu[8 * hf + r] += (f2){x[r].x, x[r].x} * wv0;
          accu[8 * hf + r] += (f2){x[r].y, x[r].y} * wv1;
          accu[8 * hf + r] += (f2){x[r].z, x[r].z} * wv2;
          accu[8 * hf + r] += (f2){x[r].w, x[r].w} * wv3;
        }
      }
    }
  }

  // ---- unpack into per-unit row-pair accumulators (8 f2 = 16 rows each) ----
  f2 a10[8], a11[8], a20[8], a21[8];
  #pragma unroll
  for (int r2 = 0; r2 < 8; ++r2) {
    a10[r2] = (f2){accu[2 * r2].x, accu[2 * r2 + 1].x};
    a11[r2] = (f2){accu[2 * r2].y, accu[2 * r2 + 1].y};
  }
  {
    float bb0 = b2p[q0], bb1 = b2p[q1];
    #pragma unroll
    for (int r2 = 0; r2 < 8; ++r2) {
      a20[r2] = (f2){bb0, bb0};
      a21[r2] = (f2){bb1, bb1};
    }
  }

  // output state: cols (l, l+64) x rows 4rp..4rp+3
  f2 ocA[2], ocB[2];
  ocA[0] = ocA[1] = (f2){bo[l], bo[l]};
  ocB[0] = ocB[1] = (f2){bo[l + 64], bo[l + 64]};
  int r0 = b0 + 4 * rp;
  f2 ez01 = (f2){eps[(r0 + 0) * Dn + l], eps[(r0 + 1) * Dn + l]};
  f2 ez23 = (f2){eps[(r0 + 2) * Dn + l], eps[(r0 + 3) * Dn + l]};
  f2 zs01 = (f2){0.f, 0.f}, zs23 = zs01;
  f2 mus01 = zs01, mus23 = zs01, scs01 = zs01, scs23 = zs01;

  // ---- prologue: step-0 weights into current regs ----
  float4 C1c0, C1c1, C1c2, C0c0, C0c1, C0c2;    // Wq[S] for q1, q0
  float4 WB0, WB1, WB2, WB3, WB4;               // Woq[S] for col l
  {
    const float4* a4 = (const float4*)(Wq + (size_t)q1 * 12);
    C1c0 = a4[0]; C1c1 = a4[1]; C1c2 = a4[2];
    const float4* b4 = (const float4*)(Wq + (size_t)q0 * 12);
    C0c0 = b4[0]; C0c1 = b4[1]; C0c2 = b4[2];
    const float4* w4 = (const float4*)(Woq + (size_t)l * 20);
    WB0 = w4[0]; WB1 = w4[1]; WB2 = w4[2]; WB3 = w4[3]; WB4 = w4[4];
  }

  // ---- sequential loop: 3 raw barriers/step (v16 structure) ----
  #pragma clang loop unroll(disable)
  for (int i = 0; i < Dn; ++i) {
    // E: thread (rp, l==i) finalizes cols (i, i+64) for its wave's 4 rows
    if (l == i) {
      f2 p01 = ocB[0], p23 = ocB[1];
      float s0 = fmaxf(p01.x, 0.f) + __logf(1.f + __expf(-fabsf(p01.x)));
      float s1 = fmaxf(p01.y, 0.f) + __logf(1.f + __expf(-fabsf(p01.y)));
      float s2 = fmaxf(p23.x, 0.f) + __logf(1.f + __expf(-fabsf(p23.x)));
      float s3 = fmaxf(p23.y, 0.f) + __logf(1.f + __expf(-fabsf(p23.y)));
      f2 sc01 = (f2){s0, s1}, sc23 = (f2){s2, s3};
      f2 z01 = ocA[0] + sc01 * ez01;
      f2 z23 = ocA[1] + sc23 * ez23;
      float4 zq = {z01.x, z01.y, z23.x, z23.y};
      *(float4*)&zcur[4 * rp] = zq;
      zs01 = z01; zs23 = z23;
      mus01 = ocA[0]; mus23 = ocA[1];
      scs01 = sc01; scs23 = sc23;
    }
    BARRIER();                                     // bar1: z published

    int sb = (i < 8) ? 9 * i : 8 * i + 8;          // group-i base
    bool liveB = (i <= gm1s);                      // wave-uniform
    bool liveA = (i <= gm0s);
    if (liveB) {
      // FA uses prefetched C regs -- NO VMEM in this phase
      float4 za = *(const float4*)&zcur[0];
      float4 zb = *(const float4*)&zcur[4];
      float4 zc = *(const float4*)&zcur[8];
      float4 zd = *(const float4*)&zcur[12];
      f2 zz[8] = {(f2){za.x, za.y}, (f2){za.z, za.w},
                  (f2){zb.x, zb.y}, (f2){zb.z, zb.w},
                  (f2){zc.x, zc.y}, (f2){zc.z, zc.w},
                  (f2){zd.x, zd.y}, (f2){zd.z, zd.w}};
      {
        f2 wv = (f2){C1c2.y, C1c2.y};
        #pragma unroll
        for (int r2 = 0; r2 < 8; ++r2) a11[r2] += wv * zz[r2];
        if (g1 == i) {
          int pp = q1 - sb;
          #pragma unroll
          for (int s = 0; s < 4; ++s) {
            float4 h = {fmaxf(a11[2 * s].x, 0.f), fmaxf(a11[2 * s].y, 0.f),
                        fmaxf(a11[2 * s + 1].x, 0.f), fmaxf(a11[2 * s + 1].y, 0.f)};
            *(float4*)&h1g[pp][4 * s] = h;
          }
        }
      }
      if (liveA) {
        f2 wv = (f2){C0c2.y, C0c2.y};
        #pragma unroll
        for (int r2 = 0; r2 < 8; ++r2) a10[r2] += wv * zz[r2];
        if (g0 == i) {
          int pp = q0 - sb;
          #pragma unroll
          for (int s = 0; s < 4; ++s) {
            float4 h = {fmaxf(a10[2 * s].x, 0.f), fmaxf(a10[2 * s].y, 0.f),
                        fmaxf(a10[2 * s + 1].x, 0.f), fmaxf(a10[2 * s + 1].y, 0.f)};
            *(float4*)&h1g[pp][4 * s] = h;
          }
        }
      }
    }
    BARRIER();                                     // bar2: h1 published

    // prefetch step i+1's weights (in flight across MID/bar3/D/E/bar1)
    bool pldB = (i + 1 <= gm1s);
    bool pldA = (i + 1 <= gm0s);
    bool pwo  = (i + 1 < Dn);
    float4 P1c0, P1c1, P1c2, P0c0, P0c1, P0c2;
    float4 PW0, PW1, PW2, PW3, PW4;
    if (pldB) {
      const float4* a4 = (const float4*)(Wq + (size_t)(i + 1) * 6144 + (size_t)q1 * 12);
      P1c0 = a4[0]; P1c1 = a4[1]; P1c2 = a4[2];
      if (pldA) {
        const float4* b4 = (const float4*)(Wq + (size_t)(i + 1) * 6144 + (size_t)q0 * 12);
        P0c0 = b4[0]; P0c1 = b4[1]; P0c2 = b4[2];
      }
    }
    if (pwo) {
      const float4* w4 = (const float4*)(Woq + (size_t)(i + 1) * 1280 + (size_t)l * 20);
      PW0 = w4[0]; PW1 = w4[1]; PW2 = w4[2]; PW3 = w4[3]; PW4 = w4[4];
    }

    if (liveB) {
      float wA1[9] = {C1c0.x, C1c0.y, C1c0.z, C1c0.w,
                      C1c1.x, C1c1.y, C1c1.z, C1c1.w, C1c2.x};
      if (liveA) {
        float wA0[9] = {C0c0.x, C0c0.y, C0c0.z, C0c0.w,
                        C0c1.x, C0c1.y, C0c1.z, C0c1.w, C0c2.x};
        #pragma unroll
        for (int p = 0; p < 9; ++p) {
          float4 ha = *(const float4*)&h1g[p][0];
          float4 hb = *(const float4*)&h1g[p][4];
          float4 hc = *(const float4*)&h1g[p][8];
          float4 hd = *(const float4*)&h1g[p][12];
          f2 h[8] = {(f2){ha.x, ha.y}, (f2){ha.z, ha.w},
                     (f2){hb.x, hb.y}, (f2){hb.z, hb.w},
                     (f2){hc.x, hc.y}, (f2){hc.z, hc.w},
                     (f2){hd.x, hd.y}, (f2){hd.z, hd.w}};
          f2 wv1 = (f2){wA1[p], wA1[p]};
          f2 wv0 = (f2){wA0[p], wA0[p]};
          #pragma unroll
          for (int r2 = 0; r2 < 8; ++r2) {
            a21[r2] += wv1 * h[r2];
            a20[r2] += wv0 * h[r2];
          }
        }
      } else {
        #pragma unroll
        for (int p = 0; p < 9; ++p) {
          float4 ha = *(const float4*)&h1g[p][0];
          float4 hb = *(const float4*)&h1g[p][4];
          float4 hc = *(const float4*)&h1g[p][8];
          float4 hd = *(const float4*)&h1g[p][12];
          f2 h[8] = {(f2){ha.x, ha.y}, (f2){ha.z, ha.w},
                     (f2){hb.x, hb.y}, (f2){hb.z, hb.w},
                     (f2){hc.x, hc.y}, (f2){hc.z, hc.w},
                     (f2){hd.x, hd.y}, (f2){hd.z, hd.w}};
          f2 wv1 = (f2){wA1[p], wA1[p]};
          #pragma unroll
          for (int r2 = 0; r2 < 8; ++r2) a21[r2] += wv1 * h[r2];
        }
      }
      if (g1 == i) {
        int pp = q1 - sb;
        #pragma unroll
        for (int s = 0; s < 4; ++s) {
          float4 h = {fmaxf(a21[2 * s].x, 0.f), fmaxf(a21[2 * s].y, 0.f),
                      fmaxf(a21[2 * s + 1].x, 0.f), fmaxf(a21[2 * s + 1].y, 0.f)};
          *(float4*)&h2g[pp][4 * s] = h;
        }
      }
      if (liveA && g0 == i) {
        int pp = q0 - sb;
        #pragma unroll
        for (int s = 0; s < 4; ++s) {
          float4 h = {fmaxf(a20[2 * s].x, 0.f), fmaxf(a20[2 * s].y, 0.f),
                      fmaxf(a20[2 * s + 1].x, 0.f), fmaxf(a20[2 * s + 1].y, 0.f)};
          *(float4*)&h2g[pp][4 * s] = h;
        }
      }
    }
    BARRIER();                                     // bar3: h2 published

    // D: oacc += h2(group i) . Wo (prefetched WB regs; slot-8 zeroed in prep)
    {
      float wBa[9] = {WB0.x, WB0.y, WB0.z, WB0.w, WB1.x, WB1.y, WB1.z, WB1.w, WB2.x};
      float wBb[9] = {WB2.z, WB2.w, WB3.x, WB3.y, WB3.z, WB3.w, WB4.x, WB4.y, WB4.z};
      #pragma unroll
      for (int p = 0; p < 9; ++p) {
        float4 hq = *(const float4*)&h2g[p][4 * rp];   // wave-uniform addr
        f2 h01 = (f2){hq.x, hq.y}, h23 = (f2){hq.z, hq.w};
        f2 wa = (f2){wBa[p], wBa[p]}, wb = (f2){wBb[p], wBb[p]};
        ocA[0] += wa * h01; ocA[1] += wa * h23;
        ocB[0] += wb * h01; ocB[1] += wb * h23;
      }
    }

    // rotate prefetched regs into current (consumed after next bar1/bar3)
    if (pldB) {
      C1c0 = P1c0; C1c1 = P1c1; C1c2 = P1c2;
      if (pldA) { C0c0 = P0c0; C0c1 = P0c1; C0c2 = P0c2; }
    }
    if (pwo) { WB0 = PW0; WB1 = PW1; WB2 = PW2; WB3 = PW3; WB4 = PW4; }
  }

  // ---- epilogue: thread (rp, l) holds z/mu/sc for rows 4rp..4rp+3, col l ----
  out[(r0 + 0) * Dn + l] = zs01.x;
  out[(r0 + 1) * Dn + l] = zs01.y;
  out[(r0 + 2) * Dn + l] = zs23.x;
  out[(r0 + 3) * Dn + l] = zs23.y;
  out[BD + (r0 + 0) * Dn + l] = mus01.x;
  out[BD + (r0 + 1) * Dn + l] = mus01.y;
  out[BD + (r0 + 2) * Dn + l] = mus23.x;
  out[BD + (r0 + 3) * Dn + l] = mus23.y;
  out[2 * BD + (r0 + 0) * Dn + l] = scs01.x;
  out[2 * BD + (r0 + 1) * Dn + l] = scs01.y;
  out[2 * BD + (r0 + 2) * Dn + l] = scs23.x;
  out[2 * BD + (r0 + 3) * Dn + l] = scs23.y;
}

extern "C" void kernel_launch(void* const* d_in, const int* in_sizes, int n_in,
                              void* d_out, int out_size, void* d_ws, size_t ws_size,
                              hipStream_t stream) {
  const float* context = (const float*)d_in[0];
  const float* eps     = (const float*)d_in[1];
  const float* W1      = (const float*)d_in[2];
  const float* b1      = (const float*)d_in[3];
  const float* Wc      = (const float*)d_in[4];
  const float* W2      = (const float*)d_in[5];
  const float* b2      = (const float*)d_in[6];
  const float* Wo      = (const float*)d_in[7];
  const float* bo      = (const float*)d_in[8];
  float* out = (float*)d_out;

  float* ws   = (float*)d_ws;
  float* Wq   = ws;                        // 393216 floats
  float* Woq  = Wq + WQ_SZ;                //  81920
  float* WcpT = Woq + WOQ_SZ;              // 131072
  float* b1p  = WcpT + WCP_SZ;             //    512
  float* b2p  = b1p + 512;                 //    512
  // total ws use: ~2.4 MB (L2-resident)

  prep_kernel<<<(R5e + 255) / 256, 256, 0, stream>>>(
      W1, Wc, W2, Wo, b1, b2, Wq, Woq, WcpT, b1p, b2p);
  made_pk_kernel<<<Bn / Rn, 256, 0, stream>>>(context, WcpT, b1p, Wq, Woq,
                                              b2p, bo, eps, out);
}